// Round 1
// baseline (85.686 us; speedup 1.0000x reference)
//
#include <hip/hip_runtime.h>

#define NQ 4
#define NL 2
#define NGATES (NL * NQ)

// ---------------------------------------------------------------------------
// Kernel 1: compute the 8 shared Rot-gate matrices (2x2 complex each) from
// weights into d_ws. Runs once per launch, 8 threads of work.
// Layout per gate: [u00r,u00i, u01r,u01i, u10r,u10i, u11r,u11i]
// ---------------------------------------------------------------------------
__global__ void prep_gates(const float* __restrict__ w, float* __restrict__ g) {
    int t = threadIdx.x;
    if (t >= NGATES) return;
    float phi   = w[t * 3 + 0];
    float theta = w[t * 3 + 1];
    float omega = w[t * 3 + 2];
    float st, ct, sa, ca, sb, cb;
    sincosf(theta * 0.5f, &st, &ct);
    sincosf((phi + omega) * 0.5f, &sa, &ca);
    sincosf((phi - omega) * 0.5f, &sb, &cb);
    float* o = g + t * 8;
    // U00 = e^{-i(phi+omega)/2} * cos(th/2)
    o[0] = ca * ct;  o[1] = -sa * ct;
    // U01 = -e^{+i(phi-omega)/2} * sin(th/2)
    o[2] = -cb * st; o[3] = -sb * st;
    // U10 = e^{-i(phi-omega)/2} * sin(th/2)
    o[4] = cb * st;  o[5] = -sb * st;
    // U11 = e^{+i(phi+omega)/2} * cos(th/2)
    o[6] = ca * ct;  o[7] = sa * ct;
}

// ---------------------------------------------------------------------------
// Kernel 2: one thread = one sample. 16 complex amplitudes in registers.
// Wire w <-> bit stride (8 >> w)  (wire 0 is the MSB of the flat index).
// ---------------------------------------------------------------------------
__global__ __launch_bounds__(256) void qsim(const float* __restrict__ x,
                                            const float* __restrict__ g,
                                            float* __restrict__ out, int B) {
    int i = blockIdx.x * blockDim.x + threadIdx.x;
    if (i >= B) return;

    // x row is 8 floats; only the first 4 are used.
    float4 xv = *reinterpret_cast<const float4*>(x + (size_t)i * 8);

    const float HALF_PI = 1.57079632679489662f;
    float cw[NQ], sw[NQ];
    {
        float a;
        a = tanhf(xv.x) * HALF_PI; __sincosf(a, &sw[0], &cw[0]);
        a = tanhf(xv.y) * HALF_PI; __sincosf(a, &sw[1], &cw[1]);
        a = tanhf(xv.z) * HALF_PI; __sincosf(a, &sw[2], &cw[2]);
        a = tanhf(xv.w) * HALF_PI; __sincosf(a, &sw[3], &cw[3]);
    }

    // Initial product state (all real): amp[k] = prod_w (bit ? sin : cos)
    float sr[16], si[16];
#pragma unroll
    for (int k = 0; k < 16; ++k) {
        float v = ((k & 8) ? sw[0] : cw[0]) *
                  ((k & 4) ? sw[1] : cw[1]) *
                  ((k & 2) ? sw[2] : cw[2]) *
                  ((k & 1) ? sw[3] : cw[3]);
        sr[k] = v;
        si[k] = 0.0f;
    }

#pragma unroll
    for (int l = 0; l < NL; ++l) {
        // --- Rot gates on each wire ---
#pragma unroll
        for (int w = 0; w < NQ; ++w) {
            const float* u = g + (l * NQ + w) * 8;
            float u00r = u[0], u00i = u[1], u01r = u[2], u01i = u[3];
            float u10r = u[4], u10i = u[5], u11r = u[6], u11i = u[7];
            int st = 8 >> w;
#pragma unroll
            for (int k = 0; k < 16; ++k) {
                if (k & st) continue;   // k = low index of the pair
                int k1 = k + st;
                float ar = sr[k],  ai = si[k];
                float br = sr[k1], bi = si[k1];
                // new_a = u00*a + u01*b
                sr[k]  = u00r * ar - u00i * ai + u01r * br - u01i * bi;
                si[k]  = u00r * ai + u00i * ar + u01r * bi + u01i * br;
                // new_b = u10*a + u11*b
                sr[k1] = u10r * ar - u10i * ai + u11r * br - u11i * bi;
                si[k1] = u10r * ai + u10i * ar + u11r * bi + u11i * br;
            }
        }
        // --- CNOT ring: (0,1),(1,2),(2,3),(3,0), sequential ---
#pragma unroll
        for (int c = 0; c < NQ; ++c) {
            int t  = (c + 1) & 3;
            int cs = 8 >> c;
            int ts = 8 >> t;
#pragma unroll
            for (int k = 0; k < 16; ++k) {
                if ((k & cs) && !(k & ts)) {
                    int k1 = k | ts;
                    float tr = sr[k]; sr[k] = sr[k1]; sr[k1] = tr;
                    float ti = si[k]; si[k] = si[k1]; si[k1] = ti;
                }
            }
        }
    }

    // Probabilities and per-wire Z expectations
    float p[16];
#pragma unroll
    for (int k = 0; k < 16; ++k) p[k] = sr[k] * sr[k] + si[k] * si[k];

    float4 o = {0.f, 0.f, 0.f, 0.f};
#pragma unroll
    for (int k = 0; k < 16; ++k) {
        o.x += (k & 8) ? -p[k] : p[k];
        o.y += (k & 4) ? -p[k] : p[k];
        o.z += (k & 2) ? -p[k] : p[k];
        o.w += (k & 1) ? -p[k] : p[k];
    }
    *reinterpret_cast<float4*>(out + (size_t)i * 4) = o;
}

extern "C" void kernel_launch(void* const* d_in, const int* in_sizes, int n_in,
                              void* d_out, int out_size, void* d_ws, size_t ws_size,
                              hipStream_t stream) {
    const float* x   = (const float*)d_in[0];
    const float* wts = (const float*)d_in[1];
    float* out       = (float*)d_out;
    float* gates     = (float*)d_ws;   // 64 floats

    int B = in_sizes[0] / 8;

    prep_gates<<<1, 64, 0, stream>>>(wts, gates);

    int threads = 256;
    int blocks  = (B + threads - 1) / threads;
    qsim<<<blocks, threads, 0, stream>>>(x, gates, out, B);
}

// Round 2
// 77.758 us; speedup vs baseline: 1.1020x; 1.1020x over previous
//
#include <hip/hip_runtime.h>

#define NQ 4
#define NL 2

// ---------------------------------------------------------------------------
// Kernel 1: build the full 16x16 complex circuit unitary U from weights.
// Thread k pushes basis state e_k through the circuit -> column k of U.
// ws layout: ws[k*32 + 2*j] = Re U[j,k], ws[k*32 + 2*j + 1] = Im U[j,k]
// (column-contiguous, re/im interleaved so the main kernel can float2-load).
// ---------------------------------------------------------------------------
__global__ void prep_unitary(const float* __restrict__ w, float* __restrict__ g) {
    int k = threadIdx.x;
    if (k >= 16) return;

    float sr[16], si[16];
#pragma unroll
    for (int j = 0; j < 16; ++j) { sr[j] = 0.f; si[j] = 0.f; }
    sr[k] = 1.f;

#pragma unroll
    for (int l = 0; l < NL; ++l) {
        // Rot gates on each wire (each thread recomputes the 2x2 -- trivial)
#pragma unroll
        for (int wi = 0; wi < NQ; ++wi) {
            float phi = w[(l * NQ + wi) * 3 + 0];
            float th  = w[(l * NQ + wi) * 3 + 1];
            float om  = w[(l * NQ + wi) * 3 + 2];
            float st, ct, sa, ca, sb, cb;
            sincosf(th * 0.5f, &st, &ct);
            sincosf((phi + om) * 0.5f, &sa, &ca);
            sincosf((phi - om) * 0.5f, &sb, &cb);
            float u00r =  ca * ct, u00i = -sa * ct;
            float u01r = -cb * st, u01i = -sb * st;
            float u10r =  cb * st, u10i = -sb * st;
            float u11r =  ca * ct, u11i =  sa * ct;
            int stb = 8 >> wi;
#pragma unroll
            for (int a = 0; a < 16; ++a) {
                if (a & stb) continue;
                int b = a + stb;
                float ar = sr[a], ai = si[a], br = sr[b], bi = si[b];
                sr[a] = u00r * ar - u00i * ai + u01r * br - u01i * bi;
                si[a] = u00r * ai + u00i * ar + u01r * bi + u01i * br;
                sr[b] = u10r * ar - u10i * ai + u11r * br - u11i * bi;
                si[b] = u10r * ai + u10i * ar + u11r * bi + u11i * br;
            }
        }
        // CNOT ring (0,1)(1,2)(2,3)(3,0)
#pragma unroll
        for (int c = 0; c < NQ; ++c) {
            int t = (c + 1) & 3, cs = 8 >> c, ts = 8 >> t;
#pragma unroll
            for (int a = 0; a < 16; ++a) {
                if ((a & cs) && !(a & ts)) {
                    int b = a | ts;
                    float tr = sr[a]; sr[a] = sr[b]; sr[b] = tr;
                    float ti = si[a]; si[a] = si[b]; si[b] = ti;
                }
            }
        }
    }

    float* o = g + k * 32;
#pragma unroll
    for (int j = 0; j < 16; ++j) { o[2 * j] = sr[j]; o[2 * j + 1] = si[j]; }
}

// ---------------------------------------------------------------------------
// Kernel 2: one thread = one sample.
//   s0 = product state from x (real), psi = U * s0 (512 real FMAs, float2
//   packed), then per-wire Z expectations from |psi|^2.
// ---------------------------------------------------------------------------
__device__ __forceinline__ float fast_tanh(float v) {
    // 1 - 2/(1+e^{2v}); exact at saturation (e^inf -> inf -> 1, e^-inf -> -1)
    float e = __expf(2.0f * v);
    return 1.0f - 2.0f * __frcp_rn(1.0f + e);
}

__global__ __launch_bounds__(256) void qsim(const float* __restrict__ x,
                                            const float* __restrict__ g,
                                            float* __restrict__ out, int B) {
    int i = blockIdx.x * blockDim.x + threadIdx.x;
    if (i >= B) return;

    float4 xv = *reinterpret_cast<const float4*>(x + (size_t)i * 8);

    const float HALF_PI = 1.57079632679489662f;
    float c[NQ], s[NQ];
    {
        float a;
        a = fast_tanh(xv.x) * HALF_PI; __sincosf(a, &s[0], &c[0]);
        a = fast_tanh(xv.y) * HALF_PI; __sincosf(a, &s[1], &c[1]);
        a = fast_tanh(xv.z) * HALF_PI; __sincosf(a, &s[2], &c[2]);
        a = fast_tanh(xv.w) * HALF_PI; __sincosf(a, &s[3], &c[3]);
    }

    // s0[k] = A[k>>2] * B[k&3]; A over qubits 0,1, B over qubits 2,3
    float A[4], Bq[4], s0[16];
#pragma unroll
    for (int a = 0; a < 4; ++a)
        A[a] = ((a & 2) ? s[0] : c[0]) * ((a & 1) ? s[1] : c[1]);
#pragma unroll
    for (int b = 0; b < 4; ++b)
        Bq[b] = ((b & 2) ? s[2] : c[2]) * ((b & 1) ? s[3] : c[3]);
#pragma unroll
    for (int k = 0; k < 16; ++k) s0[k] = A[k >> 2] * Bq[k & 3];

    // psi = U * s0  (columns of U are contiguous float2 pairs)
    float2 psi[16];
#pragma unroll
    for (int j = 0; j < 16; ++j) psi[j] = make_float2(0.f, 0.f);

    const float2* G = reinterpret_cast<const float2*>(g);
#pragma unroll
    for (int k = 0; k < 16; ++k) {
        float a = s0[k];
        const float2* col = G + k * 16;
#pragma unroll
        for (int j = 0; j < 16; ++j) {
            float2 u = col[j];
            psi[j].x = fmaf(a, u.x, psi[j].x);
            psi[j].y = fmaf(a, u.y, psi[j].y);
        }
    }

    float p[16];
#pragma unroll
    for (int j = 0; j < 16; ++j)
        p[j] = psi[j].x * psi[j].x + psi[j].y * psi[j].y;

    float4 o = {0.f, 0.f, 0.f, 0.f};
#pragma unroll
    for (int k = 0; k < 16; ++k) {
        o.x += (k & 8) ? -p[k] : p[k];
        o.y += (k & 4) ? -p[k] : p[k];
        o.z += (k & 2) ? -p[k] : p[k];
        o.w += (k & 1) ? -p[k] : p[k];
    }
    *reinterpret_cast<float4*>(out + (size_t)i * 4) = o;
}

extern "C" void kernel_launch(void* const* d_in, const int* in_sizes, int n_in,
                              void* d_out, int out_size, void* d_ws, size_t ws_size,
                              hipStream_t stream) {
    const float* x   = (const float*)d_in[0];
    const float* wts = (const float*)d_in[1];
    float* out       = (float*)d_out;
    float* gates     = (float*)d_ws;   // 512 floats

    int B = in_sizes[0] / 8;

    prep_unitary<<<1, 64, 0, stream>>>(wts, gates);

    int threads = 256;
    int blocks  = (B + threads - 1) / threads;
    qsim<<<blocks, threads, 0, stream>>>(x, gates, out, B);
}

// Round 3
// 76.018 us; speedup vs baseline: 1.1272x; 1.0229x over previous
//
#include <hip/hip_runtime.h>

#define NQ 4
#define NL 2

// Symmetric-pair index tables: pair p -> (PA[p], PB[p]), PA<=PB
__constant__ const int c_PA[10] = {0,0,0,0,1,1,1,2,2,3};
__constant__ const int c_PB[10] = {0,1,2,3,1,2,3,2,3,3};

// ---------------------------------------------------------------------------
// Kernel 1: build the folded coefficient table.
//   Phase A (threads 0..15): push basis vector e_k through the circuit ->
//     column k of the 16x16 unitary U, stored in LDS.
//   Phase B (threads 0..99): fold M_w = Re(U^dag Z_w U) over the Kronecker
//     structure s0 = A (x) B into C_w[p][q] for symmetric monomial pairs.
//   Output: g[(p*10+q)*4 + w]  (float4 per (p,q): all 4 wires).
// ---------------------------------------------------------------------------
__global__ void prep_coeffs(const float* __restrict__ w, float* __restrict__ g) {
    __shared__ float Ur[16][16], Ui[16][16];   // [row j][col k]
    int t = threadIdx.x;

    if (t < 16) {
        float sr[16], si[16];
#pragma unroll
        for (int j = 0; j < 16; ++j) { sr[j] = 0.f; si[j] = 0.f; }
        sr[t] = 1.f;

#pragma unroll
        for (int l = 0; l < NL; ++l) {
#pragma unroll
            for (int wi = 0; wi < NQ; ++wi) {
                float phi = w[(l * NQ + wi) * 3 + 0];
                float th  = w[(l * NQ + wi) * 3 + 1];
                float om  = w[(l * NQ + wi) * 3 + 2];
                float st, ct, sa, ca, sb, cb;
                __sincosf(th * 0.5f, &st, &ct);
                __sincosf((phi + om) * 0.5f, &sa, &ca);
                __sincosf((phi - om) * 0.5f, &sb, &cb);
                float u00r =  ca * ct, u00i = -sa * ct;
                float u01r = -cb * st, u01i = -sb * st;
                float u10r =  cb * st, u10i = -sb * st;
                float u11r =  ca * ct, u11i =  sa * ct;
                int stb = 8 >> wi;
#pragma unroll
                for (int a = 0; a < 16; ++a) {
                    if (a & stb) continue;
                    int b = a + stb;
                    float ar = sr[a], ai = si[a], br = sr[b], bi = si[b];
                    sr[a] = u00r * ar - u00i * ai + u01r * br - u01i * bi;
                    si[a] = u00r * ai + u00i * ar + u01r * bi + u01i * br;
                    sr[b] = u10r * ar - u10i * ai + u11r * br - u11i * bi;
                    si[b] = u10r * ai + u10i * ar + u11r * bi + u11i * br;
                }
            }
#pragma unroll
            for (int c = 0; c < NQ; ++c) {
                int tt = (c + 1) & 3, cs = 8 >> c, ts = 8 >> tt;
#pragma unroll
                for (int a = 0; a < 16; ++a) {
                    if ((a & cs) && !(a & ts)) {
                        int b = a | ts;
                        float tr = sr[a]; sr[a] = sr[b]; sr[b] = tr;
                        float ti = si[a]; si[a] = si[b]; si[b] = ti;
                    }
                }
            }
        }
#pragma unroll
        for (int j = 0; j < 16; ++j) { Ur[j][t] = sr[j]; Ui[j][t] = si[j]; }
    }

    __syncthreads();

    if (t < 100) {
        int p = t / 10, q = t - p * 10;
        int a = c_PA[p], a2 = c_PB[p];
        int b = c_PA[q], b2 = c_PB[q];
        int k1 = a * 4 + b,  k2 = a2 * 4 + b2;   // pairing (a,b)-(a',b')
        int k3 = a * 4 + b2, k4 = a2 * 4 + b;    // pairing (a,b')-(a',b)
        bool da = (a == a2), db = (b == b2);
        float m1w = (da && db) ? 1.f : 2.f;      // multiplicity of pairing 1
        float m2w = (!da && !db) ? 2.f : 0.f;    // pairing 2 only when distinct

        float acc0 = 0.f, acc1 = 0.f, acc2 = 0.f, acc3 = 0.f;
        for (int j = 0; j < 16; ++j) {
            float v1 = Ur[j][k1] * Ur[j][k2] + Ui[j][k1] * Ui[j][k2];
            float v2 = Ur[j][k3] * Ur[j][k4] + Ui[j][k3] * Ui[j][k4];
            float v = m1w * v1 + m2w * v2;
            acc0 += (j & 8) ? -v : v;
            acc1 += (j & 4) ? -v : v;
            acc2 += (j & 2) ? -v : v;
            acc3 += (j & 1) ? -v : v;
        }
        float* o = g + t * 4;
        o[0] = acc0; o[1] = acc1; o[2] = acc2; o[3] = acc3;
    }
}

// ---------------------------------------------------------------------------
// Kernel 2: one thread = one sample.
//   A,B real 4-vectors from x; out = sum_{p,q} (Aq2[p]*Bq2[q]) * C[p][q]
//   with C rows float4 over the 4 output wires.
// ---------------------------------------------------------------------------
typedef float v4f __attribute__((ext_vector_type(4)));

__device__ __forceinline__ float fast_tanh(float v) {
    float e = __expf(2.0f * v);
    return 1.0f - 2.0f * __frcp_rn(1.0f + e);
}

__global__ __launch_bounds__(256) void qsim(const float* __restrict__ x,
                                            const float* __restrict__ g,
                                            float* __restrict__ out, int B) {
    int i = blockIdx.x * blockDim.x + threadIdx.x;
    if (i >= B) return;

    float4 xv = *reinterpret_cast<const float4*>(x + (size_t)i * 8);

    const float HALF_PI = 1.57079632679489662f;
    float c[NQ], s[NQ];
    {
        float a;
        a = fast_tanh(xv.x) * HALF_PI; __sincosf(a, &s[0], &c[0]);
        a = fast_tanh(xv.y) * HALF_PI; __sincosf(a, &s[1], &c[1]);
        a = fast_tanh(xv.z) * HALF_PI; __sincosf(a, &s[2], &c[2]);
        a = fast_tanh(xv.w) * HALF_PI; __sincosf(a, &s[3], &c[3]);
    }

    float A[4], Bv[4];
#pragma unroll
    for (int a = 0; a < 4; ++a)
        A[a] = ((a & 2) ? s[0] : c[0]) * ((a & 1) ? s[1] : c[1]);
#pragma unroll
    for (int b = 0; b < 4; ++b)
        Bv[b] = ((b & 2) ? s[2] : c[2]) * ((b & 1) ? s[3] : c[3]);

    float Aq2[10], Bq2[10];
    {
        const int PA[10] = {0,0,0,0,1,1,1,2,2,3};
        const int PB[10] = {0,1,2,3,1,2,3,2,3,3};
#pragma unroll
        for (int p = 0; p < 10; ++p) {
            Aq2[p] = A[PA[p]] * A[PB[p]];
            Bq2[p] = Bv[PA[p]] * Bv[PB[p]];
        }
    }

    const v4f* C = reinterpret_cast<const v4f*>(g);
    v4f acc = {0.f, 0.f, 0.f, 0.f};
#pragma unroll
    for (int p = 0; p < 10; ++p) {
        float ap = Aq2[p];
#pragma unroll
        for (int q = 0; q < 10; ++q) {
            float m = ap * Bq2[q];
            acc += m * C[p * 10 + q];
        }
    }

    *reinterpret_cast<v4f*>(out + (size_t)i * 4) = acc;
}

extern "C" void kernel_launch(void* const* d_in, const int* in_sizes, int n_in,
                              void* d_out, int out_size, void* d_ws, size_t ws_size,
                              hipStream_t stream) {
    const float* x   = (const float*)d_in[0];
    const float* wts = (const float*)d_in[1];
    float* out       = (float*)d_out;
    float* coefs     = (float*)d_ws;   // 400 floats

    int B = in_sizes[0] / 8;

    prep_coeffs<<<1, 128, 0, stream>>>(wts, coefs);

    int threads = 256;
    int blocks  = (B + threads - 1) / threads;
    qsim<<<blocks, threads, 0, stream>>>(x, coefs, out, B);
}